// Round 16
// baseline (267.018 us; speedup 1.0000x reference)
//
#include <hip/hip_runtime.h>

typedef unsigned short u16;
typedef unsigned int u32;
typedef __attribute__((ext_vector_type(8))) short short8v;   // 8 bf16 MFMA frag
typedef __attribute__((ext_vector_type(4))) float f32x4;
typedef __attribute__((ext_vector_type(2))) float f32x2;
typedef __attribute__((ext_vector_type(4))) unsigned int uint4v;
typedef __attribute__((ext_vector_type(2))) unsigned int uint2v;
typedef __attribute__((ext_vector_type(8))) unsigned short us8;
typedef __attribute__((ext_vector_type(4))) unsigned short us4;

#define B_   4
#define S_   19950
#define C_   256
#define NH   8
#define DH   32
#define BS_  (B_*S_)          // 79800

#define BM 128                // 128-row M-panels, 512-thread blocks (8 waves)
#define BN 128
#define BK 64
#define NPAN 624              // ceil(79800/128)=624, divisible by 8

__device__ __forceinline__ float bf2f(u16 u){ u32 x=((u32)u)<<16; float f; __builtin_memcpy(&f,&x,4); return f; }
__device__ __forceinline__ u16 f2bf(float f){ u32 x; __builtin_memcpy(&x,&f,4); x += 0x7fffu + ((x>>16)&1u); return (u16)(x>>16); }
__device__ __forceinline__ u32 cvtpk(float a, float b){ u32 r; asm("v_cvt_pk_bf16_f32 %0, %1, %2" : "=v"(r) : "v"(a), "v"(b)); return r; }
__device__ __forceinline__ f32x2 pkfma(f32x2 a, f32x2 b, f32x2 d){
  asm("v_pk_fma_f32 %0, %1, %2, %0" : "+v"(d) : "v"(a), "v"(b)); return d;
}
__device__ __forceinline__ f32x2 unpk(u32 p){
  uint2v u; u.x = p<<16; u.y = p & 0xffff0000u; return __builtin_bit_cast(f32x2, u);
}

// ====== MFMA GEMM core: round-13 per-step structure, 8 waves (512 thr), 128x128 tile ======
// MODE 0: A=value f32 -> v bf16 permuted (b,h,s,dh)
// MODE 1: A=query f32 -> soff/sattn HEAD-MAJOR [(h*4+b)][q][24|12]
// MODE 2: A=tmp bf16  -> out f32.
// A via async global_load_lds (linear dest, inverse-swizzled source, XOR on read);
// B reg-staged f32 -> cvt_pk bf16 -> swizzled ds_write; loadB(t+1) issued after writeB(t).
template<int MODE>
__device__ __forceinline__ void gemm_core(int g, u32* smem,
    const void* __restrict__ Aany, const float* __restrict__ Wmain,
    const float* __restrict__ Wattn, const float* __restrict__ bmain,
    const float* __restrict__ battn, void* __restrict__ out0, u16* __restrict__ out1)
{
  constexpr int NX = (MODE==1) ? 3 : 2;
  float* Asf = (float*)smem;                        // MODE0/1: f32[128][64]  32KB
  u16*  Asb  = (u16*)smem;                          // MODE2:   bf16[128][64] 16KB
  u32*  Bs   = smem + ((MODE==2) ? 4096 : 8192);    // bf16[128][64] 16KB

  const int tid = threadIdx.x;                      // 0..511
  const int x = (g>>3) % NX;
  const int y = ((g>>3)/NX)*8 + (g&7);   // XCD-paired: col-blocks of one A-panel 8 apart -> same XCD
  const int m0 = y * BM;
  const int n0 = x * BN;
  const int lane = tid & 63;
  const int wid  = tid >> 6;                        // 0..7
  const int wm = wid >> 1, wn = wid & 1;            // 4 m-quarters x 2 n-halves
  const int ln15 = lane & 15, ln4 = lane >> 4;

  f32x4 acc[2][4];
  #pragma unroll
  for (int i=0;i<2;++i){
    #pragma unroll
    for (int j=0;j<4;++j) acc[i][j] = (f32x4){0.f,0.f,0.f,0.f};
  }

  f32x4 bvv[4];
  auto loadB = [&](int k0){
    #pragma unroll
    for (int i=0;i<4;++i){
      const int ct = tid + 512*i;
      const int row = ct >> 4, c = ct & 15;
      const int n = n0 + row;
      f32x4 vv = (f32x4){0.f,0.f,0.f,0.f};
      if constexpr (MODE==1) {
        if (n < 192)      vv = *(const f32x4*)(Wmain + (size_t)n*C_ + k0 + c*4);
        else if (n < 288) vv = *(const f32x4*)(Wattn + (size_t)(n-192)*C_ + k0 + c*4);
      } else {
        vv = *(const f32x4*)(Wmain + (size_t)n*C_ + k0 + c*4);
      }
      bvv[i] = vv;
    }
  };

  loadB(0);   // prologue

  #pragma unroll
  for (int kt=0; kt<4; ++kt) {
    const int k0 = kt*BK;
    // ---- A async DMA to LDS (linear dest, inverse-swizzled source) ----
    if constexpr (MODE==2) {
      const u16* Ab = (const u16*)Aany;
      #pragma unroll
      for (int i=0;i<2;++i){
        const int rl = wid*16 + i*8 + (lane>>3);       // row 0..127
        const int rg = min(m0 + rl, BS_-1);
        const int c = lane & 7, cs = c ^ (rl & 7);
        __builtin_amdgcn_global_load_lds(Ab + (size_t)rg*C_ + k0 + cs*8,
            &Asb[(wid*16 + i*8)*64], 16, 0, 0);
      }
    } else {
      const float* Ab = (const float*)Aany;
      #pragma unroll
      for (int i=0;i<4;++i){
        const int rl = wid*16 + i*4 + (lane>>4);       // row 0..127
        const int rg = min(m0 + rl, BS_-1);
        const int c = lane & 15, cs = c ^ (rl & 15);
        __builtin_amdgcn_global_load_lds(Ab + (size_t)rg*C_ + k0 + cs*4,
            &Asf[(wid*16 + i*4)*64], 16, 0, 0);
      }
    }
    // ---- B cvt + swizzled LDS write (waits bvv), then issue next B loads ----
    #pragma unroll
    for (int i=0;i<4;++i){
      const int ct = tid + 512*i;
      const int row = ct >> 4, c = ct & 15;
      const u32 p0 = cvtpk(bvv[i].x, bvv[i].y), p1 = cvtpk(bvv[i].z, bvv[i].w);
      const int cc = c >> 1;
      uint2v pk; pk.x = p0; pk.y = p1;
      *(uint2v*)&Bs[row*32 + ((cc ^ (row&7))<<2) + (c&1)*2] = pk;
    }
    if (kt < 3) loadB(k0 + BK);   // in flight across sync+compute+sync
    __syncthreads();   // drains A-DMA (vmcnt) + B writes (lgkmcnt)
    // ---- compute: 2 k-sub of 32, 2x4 frags per wave ----
    #pragma unroll
    for (int ks=0; ks<2; ++ks) {
      short8v af[2], bfr[4];
      #pragma unroll
      for (int mi=0;mi<2;++mi){
        const int row = wm*32 + mi*16 + ln15;
        if constexpr (MODE==2) {
          const int c = ks*4 + ln4;
          af[mi] = *(const short8v*)&Asb[row*64 + ((c ^ (row&7))<<3)];
        } else {
          const int ch = ks*8 + ln4*2;
          const int c1 = ch ^ (row&15), c2 = (ch+1) ^ (row&15);
          const f32x4 lo = *(const f32x4*)&Asf[row*64 + c1*4];
          const f32x4 hi = *(const f32x4*)&Asf[row*64 + c2*4];
          uint4v uu;
          uu.x = cvtpk(lo.x, lo.y); uu.y = cvtpk(lo.z, lo.w);
          uu.z = cvtpk(hi.x, hi.y); uu.w = cvtpk(hi.z, hi.w);
          af[mi] = __builtin_bit_cast(short8v, uu);
        }
      }
      #pragma unroll
      for (int ni=0;ni<4;++ni){
        const int row = wn*64 + ni*16 + ln15;
        const int c = ks*4 + ln4;
        bfr[ni] = *(const short8v*)&Bs[row*32 + ((c ^ (row&7))<<2)];
      }
      #pragma unroll
      for (int mi=0;mi<2;++mi){
        #pragma unroll
        for (int ni=0;ni<4;++ni)
          acc[mi][ni] = __builtin_amdgcn_mfma_f32_16x16x32_bf16(af[mi], bfr[ni], acc[mi][ni], 0, 0, 0);
      }
    }
    __syncthreads();
  }

  // ==== epilogue via LDS repack (round-13 validated layouts, 8-wave indexing) ====
  if constexpr (MODE==2) {
    // f32 out, four 32-row passes ([32][132] f32 = 16.9KB <= 32KB), waves wm==p write pass p
    float* Cs = (float*)smem;
    float* outp = (float*)out0;
    #pragma unroll
    for (int p=0;p<4;++p){
      if (wm == p) {
        #pragma unroll
        for (int mi=0;mi<2;++mi){
          #pragma unroll
          for (int ni=0;ni<4;++ni){
            const int col = wn*64 + ni*16 + ln15;
            const float bv = bmain[n0 + col];
            #pragma unroll
            for (int j=0;j<4;++j){
              const int rl = mi*16 + ln4*4 + j;         // row within pass
              Cs[rl*132 + col] = acc[mi][ni][j] + bv;
            }
          }
        }
      }
      __syncthreads();
      #pragma unroll
      for (int i=0;i<2;++i){
        const int c = i*512 + tid;                      // 1024 chunks of 4 f32
        const int row = c >> 5, ch = c & 31;
        const int m = m0 + p*32 + row;
        if (m < BS_) {
          const f32x4 vv = *(const f32x4*)&Cs[row*132 + ch*4];
          *(f32x4*)(outp + (size_t)m*C_ + n0 + ch*4) = vv;
        }
      }
      __syncthreads();
    }
  } else {
    // bf16 tile [128][136] u16 = 34.8KB <= 48KB
    u16* Cs = (u16*)smem;
    #pragma unroll
    for (int mi=0;mi<2;++mi){
      #pragma unroll
      for (int ni=0;ni<4;++ni){
        const int col = wn*64 + ni*16 + ln15;
        const int n = n0 + col;
        if (MODE==1 && n >= 288) continue;
        float bias;
        if constexpr (MODE==1) bias = (n < 192) ? bmain[n] : battn[n-192];
        else                   bias = bmain[n];
        if (MODE==1 && n >= 192) {
          #pragma unroll
          for (int j=0;j<4;++j){
            const int row = wm*32 + mi*16 + ln4*4 + j;
            const float vv = acc[mi][ni][j] + bias;
            float mx = vv;
            mx = fmaxf(mx, __shfl_xor(mx, 1));
            mx = fmaxf(mx, __shfl_xor(mx, 2));
            const float e = __expf(vv - mx);
            float ssum = e;
            ssum += __shfl_xor(ssum, 1);
            ssum += __shfl_xor(ssum, 2);
            Cs[row*136 + col] = f2bf(e/ssum);
          }
        } else {
          #pragma unroll
          for (int j=0;j<4;++j){
            const int row = wm*32 + mi*16 + ln4*4 + j;
            Cs[row*136 + col] = f2bf(acc[mi][ni][j] + bias);
          }
        }
      }
    }
    __syncthreads();
    #pragma unroll
    for (int i=0;i<4;++i){
      const int c = i*512 + tid;                // 2048 chunks of 8 bf16
      const int row = c >> 4, ch = c & 15;
      const int m = m0 + row;
      if (m >= BS_) continue;
      const int colg = n0 + ch*8;
      const int bq = m / S_, sq = m - bq*S_;
      if constexpr (MODE==0) {
        const uint4v vv = *(const uint4v*)&Cs[row*136 + ch*8];
        u16* vout = (u16*)out0;
        const int h = colg >> 5, dh0 = colg & 31;
        *(uint4v*)(vout + ((size_t)(bq*NH+h)*S_ + sq)*DH + dh0) = vv;
      } else {
        if (colg < 192) {
          const uint4v vv = *(const uint4v*)&Cs[row*136 + ch*8];
          u16* soff = (u16*)out0;
          const int hh = colg / 24, cc = colg - hh*24;
          *(uint4v*)(soff + (((size_t)hh*4 + bq)*S_ + sq)*24 + cc) = vv;
        } else if (colg < 288) {
          #pragma unroll
          for (int half=0; half<2; ++half){
            const int nl2 = colg + half*4 - 192;
            const int hh = nl2 / 12, cc = nl2 - hh*12;
            const uint2v vv = *(const uint2v*)&Cs[row*136 + ch*8 + half*4];
            *(uint2v*)(out1 + (((size_t)hh*4 + bq)*S_ + sq)*12 + cc) = vv;
          }
        }
      }
    }
  }
}

// ---- FUSED projections: blocks [0,1248) = vproj (MODE0), [1248,3120) = qproj (MODE1) ----
__global__ __launch_bounds__(512) void k_projF(
    const void* __restrict__ value, const float* __restrict__ Wv,
    const float* __restrict__ bv, void* __restrict__ vout,
    const void* __restrict__ query, const float* __restrict__ Wo,
    const float* __restrict__ Wa, const float* __restrict__ bo,
    const float* __restrict__ ba, void* __restrict__ soff, u16* __restrict__ sattn)
{
  __shared__ u32 smem[12288];   // 48 KB (A 32K + B 16K; epilogue tile 34.8KB reuses)
  const int g = blockIdx.x;
  if (g < 2*NPAN) gemm_core<0>(g,          smem, value, Wv, nullptr, bv, nullptr, vout, nullptr);
  else            gemm_core<1>(g - 2*NPAN, smem, query, Wo, Wa,      bo, ba,      soff, sattn);
}

__global__ __launch_bounds__(512) void k_gemm2F(const void* __restrict__ A,
    const float* __restrict__ W, const float* __restrict__ b, void* __restrict__ o)
{
  __shared__ u32 smem[8192];    // 32 KB (A bf16 16K + B 16K; epilogue pass 16.9KB)
  gemm_core<2>(blockIdx.x, smem, A, W, nullptr, b, nullptr, o, nullptr);
}

// ==== Sampler v7 (round-15 proven): head-major dense records + v4 arithmetic, cached loads ====
#define NCH 312   // ceil(19950/64) chunks of 64 queries

__global__ __launch_bounds__(256) void k_sample7(const u16* __restrict__ v,
    const u16* __restrict__ soff, const u16* __restrict__ sattn,
    const float* __restrict__ refp, u16* __restrict__ tmp)
{
  const int g = blockIdx.x;
  const int xcd = g & 7, inner = g >> 3;      // inner in [0, 4*NCH)
  const int unit = inner / NCH;               // 0..3
  const int cidx = inner - unit*NCH;
  const int bh = xcd*4 + unit;                // 4 (b,h)-slices per XCD for L2 locality
  const int b = bh >> 3, h = bh & 7;
  const int dh0 = (threadIdx.x & 3) * 8;
  const int q = cidx*64 + (threadIdx.x >> 2);
  if (q >= S_) return;
  const size_t r = (size_t)b*S_ + q;
  const float refx = refp[r*2+0], refy = refp[r*2+1];
  const char* vb = (const char*)(v + (size_t)bh * S_ * DH);

  // head-major dense records: 48B offsets + 24B weights per (h,b,q)
  const u16* sop = soff + (((size_t)h*4 + b)*S_ + q)*24;
  const u16* sap = sattn + (((size_t)h*4 + b)*S_ + q)*12;
  us8 so0 = *(const us8*)(sop);
  us8 so1 = *(const us8*)(sop + 8);
  us8 so2 = *(const us8*)(sop + 16);
  us4 sa0 = *(const us4*)(sap);
  us4 sa1 = *(const us4*)(sap + 4);
  us4 sa2 = *(const us4*)(sap + 8);
  u16 soarr[24]; u16 saarr[12];
  #pragma unroll
  for (int i=0;i<8;++i){ soarr[i]=so0[i]; soarr[8+i]=so1[i]; soarr[16+i]=so2[i]; }
  #pragma unroll
  for (int i=0;i<4;++i){ saarr[i]=sa0[i]; saarr[4+i]=sa1[i]; saarr[8+i]=sa2[i]; }

  f32x2 acc0 = (f32x2){0.f,0.f}, acc1 = acc0, acc2 = acc0, acc3 = acc0;
  const int WLs[3]={152,76,38}, HLs[3]={100,50,25}, STs[3]={0,15200,19000};
  const u32 ch2 = (u32)(dh0*2);
  #pragma unroll
  for (int l=0;l<3;++l) {
    const int Wl=WLs[l], Hl=HLs[l];
    const float rxl = refx*(float)Wl - 0.5f;   // ix = ref*W + off - 0.5 (normalizer folded)
    const float ryl = refy*(float)Hl - 0.5f;
    const char* vbl = vb + (size_t)STs[l]*DH*2;
    #pragma unroll
    for (int p=0;p<4;++p) {
      const int idx = l*4 + p;
      const float ix = rxl + bf2f(soarr[2*idx+0]);
      const float iy = ryl + bf2f(soarr[2*idx+1]);
      const float aw = bf2f(saarr[idx]);
      const float x0f = floorf(ix), y0f = floorf(iy);
      const float wx1 = ix-x0f, wy1 = iy-y0f;
      const int x0 = (int)x0f, y0 = (int)y0f;
      const int x1 = x0+1, y1 = y0+1;
      // separable zeroed weights (validity folded; aw folded into y factors)
      const float wx0z = ((u32)x0 < (u32)Wl) ? (1.f-wx1) : 0.f;
      const float wx1z = ((u32)x1 < (u32)Wl) ? wx1 : 0.f;
      const float wy0z = ((u32)y0 < (u32)Hl) ? aw*(1.f-wy1) : 0.f;
      const float wy1z = ((u32)y1 < (u32)Hl) ? aw*wy1 : 0.f;
      const int xi0 = min(max(x0,0),Wl-1), xi1 = min(max(x1,0),Wl-1);
      const int yi0 = min(max(y0,0),Hl-1), yi1 = min(max(y1,0),Hl-1);
      const u32 rb0 = (u32)(yi0*Wl)*64u + ch2;
      const u32 rb1 = (u32)(yi1*Wl)*64u + ch2;
      const uint4v t00 = *(const uint4v*)(vbl + rb0 + (u32)xi0*64u);
      const uint4v t01 = *(const uint4v*)(vbl + rb0 + (u32)xi1*64u);
      const uint4v t10 = *(const uint4v*)(vbl + rb1 + (u32)xi0*64u);
      const uint4v t11 = *(const uint4v*)(vbl + rb1 + (u32)xi1*64u);
      const float w00 = wx0z*wy0z, w01 = wx1z*wy0z;
      const float w10 = wx0z*wy1z, w11 = wx1z*wy1z;
      f32x2 W00 = (f32x2){w00,w00}, W01 = (f32x2){w01,w01};
      f32x2 W10 = (f32x2){w10,w10}, W11 = (f32x2){w11,w11};
      acc0 = pkfma(unpk(t00.x), W00, acc0);
      acc1 = pkfma(unpk(t00.y), W00, acc1);
      acc2 = pkfma(unpk(t00.z), W00, acc2);
      acc3 = pkfma(unpk(t00.w), W00, acc3);
      acc0 = pkfma(unpk(t01.x), W01, acc0);
      acc1 = pkfma(unpk(t01.y), W01, acc1);
      acc2 = pkfma(unpk(t01.z), W01, acc2);
      acc3 = pkfma(unpk(t01.w), W01, acc3);
      acc0 = pkfma(unpk(t10.x), W10, acc0);
      acc1 = pkfma(unpk(t10.y), W10, acc1);
      acc2 = pkfma(unpk(t10.z), W10, acc2);
      acc3 = pkfma(unpk(t10.w), W10, acc3);
      acc0 = pkfma(unpk(t11.x), W11, acc0);
      acc1 = pkfma(unpk(t11.y), W11, acc1);
      acc2 = pkfma(unpk(t11.z), W11, acc2);
      acc3 = pkfma(unpk(t11.w), W11, acc3);
    }
  }
  uint4v o;
  o.x = cvtpk(acc0.x, acc0.y); o.y = cvtpk(acc1.x, acc1.y);
  o.z = cvtpk(acc2.x, acc2.y); o.w = cvtpk(acc3.x, acc3.y);
  *(uint4v*)(tmp + r*C_ + (size_t)h*DH + dh0) = o;
}

extern "C" void kernel_launch(void* const* d_in, const int* in_sizes, int n_in,
                              void* d_out, int out_size, void* d_ws, size_t ws_size,
                              hipStream_t stream) {
  (void)in_sizes; (void)n_in; (void)out_size; (void)ws_size;
  const float* query = (const float*)d_in[0];
  const float* value = (const float*)d_in[1];
  const float* refp  = (const float*)d_in[4];
  const float* W_off = (const float*)d_in[5];
  const float* b_off = (const float*)d_in[6];
  const float* W_attn= (const float*)d_in[7];
  const float* b_attn= (const float*)d_in[8];
  const float* W_val = (const float*)d_in[9];
  const float* b_val = (const float*)d_in[10];
  const float* W_out = (const float*)d_in[11];
  const float* b_out = (const float*)d_in[12];
  float* out = (float*)d_out;

  char* ws = (char*)d_ws;
  constexpr size_t V_BYTES    = (size_t)BS_*C_*2;     // 40.9 MB: v bf16 (b,h,s,dh)
  constexpr size_t SOFF_BYTES = (size_t)BS_*24*NH*2;  // 30.6 MB head-major
  constexpr size_t SATTN_BYTES= (size_t)BS_*12*NH*2;  // 15.3 MB head-major
  u16* v     = (u16*)(ws);
  u16* soff  = (u16*)(ws + V_BYTES);
  u16* sattn = (u16*)(ws + V_BYTES + SOFF_BYTES);
  u16* tmp   = (u16*)(ws + V_BYTES + SOFF_BYTES + SATTN_BYTES);

  hipLaunchKernelGGL(k_projF, dim3(5*NPAN), dim3(512), 0, stream,
                     (const void*)value, W_val, b_val, (void*)v,
                     (const void*)query, W_off, W_attn, b_off, b_attn,
                     (void*)soff, sattn);
  hipLaunchKernelGGL(k_sample7, dim3(8*4*NCH), dim3(256), 0, stream, v, soff, sattn, refp, tmp);
  hipLaunchKernelGGL(k_gemm2F, dim3(2*NPAN), dim3(512), 0, stream,
                     (const void*)tmp, W_out, b_out, (void*)out);
}

// Round 17
// 245.260 us; speedup vs baseline: 1.0887x; 1.0887x over previous
//
#include <hip/hip_runtime.h>

typedef unsigned short u16;
typedef unsigned int u32;
typedef __attribute__((ext_vector_type(8))) short short8v;   // 8 bf16 MFMA frag
typedef __attribute__((ext_vector_type(4))) float f32x4;
typedef __attribute__((ext_vector_type(2))) float f32x2;
typedef __attribute__((ext_vector_type(4))) unsigned int uint4v;
typedef __attribute__((ext_vector_type(2))) unsigned int uint2v;
typedef __attribute__((ext_vector_type(8))) unsigned short us8;
typedef __attribute__((ext_vector_type(4))) unsigned short us4;

#define B_   4
#define S_   19950
#define C_   256
#define NH   8
#define DH   32
#define BS_  (B_*S_)          // 79800

#define BM 64                 // 64-row M-panels
#define BN 128
#define BK 64
#define NPAN 1248             // padded to /8 (tail rows clamped+guarded)

__device__ __forceinline__ float bf2f(u16 u){ u32 x=((u32)u)<<16; float f; __builtin_memcpy(&f,&x,4); return f; }
__device__ __forceinline__ u16 f2bf(float f){ u32 x; __builtin_memcpy(&x,&f,4); x += 0x7fffu + ((x>>16)&1u); return (u16)(x>>16); }
__device__ __forceinline__ u32 cvtpk(float a, float b){ u32 r; asm("v_cvt_pk_bf16_f32 %0, %1, %2" : "=v"(r) : "v"(a), "v"(b)); return r; }
__device__ __forceinline__ f32x2 pkfma(f32x2 a, f32x2 b, f32x2 d){
  asm("v_pk_fma_f32 %0, %1, %2, %0" : "+v"(d) : "v"(a), "v"(b)); return d;
}
__device__ __forceinline__ f32x2 unpk(u32 p){
  uint2v u; u.x = p<<16; u.y = p & 0xffff0000u; return __builtin_bit_cast(f32x2, u);
}

// ====== MFMA GEMM core (round-13/15 PROVEN: single-buffer, B reg-prefetch, LDS-repack epilogue) ======
// MODE 0: A=value f32 -> v bf16 permuted (b,h,s,dh)
// MODE 2: A=tmp bf16  -> out f32.
template<int MODE>
__device__ __forceinline__ void gemm_core(int g, u32* smem,
    const void* __restrict__ Aany, const float* __restrict__ Wmain,
    const float* __restrict__ bmain, void* __restrict__ out0)
{
  constexpr int NX = 2;
  float* Asf = (float*)smem;                        // MODE0: f32[64][64]
  u16*  Asb  = (u16*)smem;                          // MODE2: bf16[64][64]
  u32*  Bs   = smem + ((MODE==2) ? 2048 : 4096);    // bf16[128][64]

  const int tid = threadIdx.x;
  const int x = (g>>3) % NX;
  const int y = ((g>>3)/NX)*8 + (g&7);   // XCD-paired: col-blocks of one A-panel 8 apart -> same XCD
  const int m0 = y * BM;
  const int n0 = x * BN;
  const int lane = tid & 63;
  const int wid  = tid >> 6;
  const int wm = wid >> 1, wn = wid & 1;
  const int ln15 = lane & 15, ln4 = lane >> 4;

  f32x4 acc[2][4];
  #pragma unroll
  for (int i=0;i<2;++i){
    #pragma unroll
    for (int j=0;j<4;++j) acc[i][j] = (f32x4){0.f,0.f,0.f,0.f};
  }

  f32x4 bvv[8];
  auto loadB = [&](int k0){
    #pragma unroll
    for (int i=0;i<8;++i){
      const int ct = tid + 256*i;
      const int row = ct >> 4, c = ct & 15;
      const int n = n0 + row;
      bvv[i] = *(const f32x4*)(Wmain + (size_t)n*C_ + k0 + c*4);
    }
  };

  loadB(0);   // prologue

  #pragma unroll
  for (int kt=0; kt<4; ++kt) {
    const int k0 = kt*BK;
    // ---- A async DMA to LDS (linear dest, inverse-swizzled source) ----
    if constexpr (MODE==2) {
      const u16* Ab = (const u16*)Aany;
      #pragma unroll
      for (int i=0;i<2;++i){
        const int rl = wid*16 + i*8 + (lane>>3);       // row 0..63
        const int rg = min(m0 + rl, BS_-1);
        const int c = lane & 7, cs = c ^ (rl & 7);
        __builtin_amdgcn_global_load_lds(Ab + (size_t)rg*C_ + k0 + cs*8,
            &Asb[(wid*16 + i*8)*64], 16, 0, 0);
      }
    } else {
      const float* Ab = (const float*)Aany;
      #pragma unroll
      for (int i=0;i<4;++i){
        const int rl = wid*16 + i*4 + (lane>>4);       // row 0..63
        const int rg = min(m0 + rl, BS_-1);
        const int c = lane & 15, cs = c ^ (rl & 15);
        __builtin_amdgcn_global_load_lds(Ab + (size_t)rg*C_ + k0 + cs*4,
            &Asf[(wid*16 + i*4)*64], 16, 0, 0);
      }
    }
    // ---- B cvt + swizzled LDS write (waits bvv), then issue next B loads ----
    #pragma unroll
    for (int i=0;i<8;++i){
      const int ct = tid + 256*i;
      const int row = ct >> 4, c = ct & 15;
      const u32 p0 = cvtpk(bvv[i].x, bvv[i].y), p1 = cvtpk(bvv[i].z, bvv[i].w);
      const int cc = c >> 1;
      uint2v pk; pk.x = p0; pk.y = p1;
      *(uint2v*)&Bs[row*32 + ((cc ^ (row&7))<<2) + (c&1)*2] = pk;
    }
    if (kt < 3) loadB(k0 + BK);   // in flight across sync+compute+sync
    __syncthreads();   // drains A-DMA (vmcnt) + B writes (lgkmcnt)
    // ---- compute: 2 k-sub of 32, 2x4 frags ----
    #pragma unroll
    for (int ks=0; ks<2; ++ks) {
      short8v af[2], bfr[4];
      #pragma unroll
      for (int mi=0;mi<2;++mi){
        const int row = wm*32 + mi*16 + ln15;
        if constexpr (MODE==2) {
          const int c = ks*4 + ln4;
          af[mi] = *(const short8v*)&Asb[row*64 + ((c ^ (row&7))<<3)];
        } else {
          const int ch = ks*8 + ln4*2;
          const int c1 = ch ^ (row&15), c2 = (ch+1) ^ (row&15);
          const f32x4 lo = *(const f32x4*)&Asf[row*64 + c1*4];
          const f32x4 hi = *(const f32x4*)&Asf[row*64 + c2*4];
          uint4v uu;
          uu.x = cvtpk(lo.x, lo.y); uu.y = cvtpk(lo.z, lo.w);
          uu.z = cvtpk(hi.x, hi.y); uu.w = cvtpk(hi.z, hi.w);
          af[mi] = __builtin_bit_cast(short8v, uu);
        }
      }
      #pragma unroll
      for (int ni=0;ni<4;++ni){
        const int row = wn*64 + ni*16 + ln15;
        const int c = ks*4 + ln4;
        bfr[ni] = *(const short8v*)&Bs[row*32 + ((c ^ (row&7))<<2)];
      }
      #pragma unroll
      for (int mi=0;mi<2;++mi){
        #pragma unroll
        for (int ni=0;ni<4;++ni)
          acc[mi][ni] = __builtin_amdgcn_mfma_f32_16x16x32_bf16(af[mi], bfr[ni], acc[mi][ni], 0, 0, 0);
      }
    }
    __syncthreads();
  }

  // ==== epilogue via LDS repack (round-13 validated): 16B coalesced stores ====
  if constexpr (MODE==2) {
    float* Cs = (float*)smem;
    float* outp = (float*)out0;
    #pragma unroll
    for (int p=0;p<2;++p){
      if (wm == p) {
        #pragma unroll
        for (int mi=0;mi<2;++mi){
          #pragma unroll
          for (int ni=0;ni<4;++ni){
            const int col = wn*64 + ni*16 + ln15;
            const float bv = bmain[n0 + col];
            #pragma unroll
            for (int j=0;j<4;++j){
              const int rl = mi*16 + ln4*4 + j;
              Cs[rl*132 + col] = acc[mi][ni][j] + bv;
            }
          }
        }
      }
      __syncthreads();
      #pragma unroll
      for (int i=0;i<4;++i){
        const int c = i*256 + tid;
        const int row = c >> 5, ch = c & 31;
        const int m = m0 + p*32 + row;
        if (m < BS_) {
          const f32x4 vv = *(const f32x4*)&Cs[row*132 + ch*4];
          *(f32x4*)(outp + (size_t)m*C_ + n0 + ch*4) = vv;
        }
      }
      __syncthreads();
    }
  } else {
    u16* Cs = (u16*)smem;
    #pragma unroll
    for (int mi=0;mi<2;++mi){
      #pragma unroll
      for (int ni=0;ni<4;++ni){
        const int col = wn*64 + ni*16 + ln15;
        const int n = n0 + col;
        const float bias = bmain[n];
        #pragma unroll
        for (int j=0;j<4;++j){
          const int row = wm*32 + mi*16 + ln4*4 + j;
          Cs[row*136 + col] = f2bf(acc[mi][ni][j] + bias);
        }
      }
    }
    __syncthreads();
    #pragma unroll
    for (int i=0;i<4;++i){
      const int c = i*256 + tid;
      const int row = c >> 4, ch = c & 15;
      const int m = m0 + row;
      if (m >= BS_) continue;
      const int colg = n0 + ch*8;
      const int bq = m / S_, sq = m - bq*S_;
      const uint4v vv = *(const uint4v*)&Cs[row*136 + ch*8];
      u16* vout = (u16*)out0;
      const int h = colg >> 5, dh0 = colg & 31;
      *(uint4v*)(vout + ((size_t)(bq*NH+h)*S_ + sq)*DH + dh0) = vv;
    }
  }
}

// ---- vproj only (qproj fused into sampler) ----
__global__ __launch_bounds__(256) void k_projF(
    const void* __restrict__ value, const float* __restrict__ Wv,
    const float* __restrict__ bv, void* __restrict__ vout)
{
  __shared__ u32 smem[8192];   // 32 KB
  gemm_core<0>(blockIdx.x, smem, value, Wv, bv, vout);
}

__global__ __launch_bounds__(256) void k_gemm2F(const void* __restrict__ A,
    const float* __restrict__ W, const float* __restrict__ b, void* __restrict__ o)
{
  __shared__ u32 smem[6144];   // 24 KB
  gemm_core<2>(blockIdx.x, smem, A, W, b, o);
}

// ==== Fused sampler: phase 1 = per-(head,64q) 64x36x256 MFMA qproj (+softmax) into LDS;
//      phase 2 = v7 gather reading offset/weight records from LDS ====
#define NCH 312   // ceil(19950/64) chunks of 64 queries

__global__ __launch_bounds__(256) void k_sampleQ(const u16* __restrict__ v,
    const float* __restrict__ query,
    const float* __restrict__ W_off, const float* __restrict__ b_off,
    const float* __restrict__ W_attn, const float* __restrict__ b_attn,
    const float* __restrict__ refp, u16* __restrict__ tmp)
{
  __shared__ u32 smem[5632];          // 22.5 KB: Q f32[64][64] 16K + W bf16[48][64] 6K
  float* QsF = (float*)smem;
  u32*  Ws   = smem + 4096;
  u16*  rec  = (u16*)smem;            // [64][40] bf16, overlaps QsF (dead after GEMM)

  const int g = blockIdx.x;
  const int xcd = g & 7, inner = g >> 3;
  const int unit = inner / NCH;
  const int cidx = inner - unit*NCH;
  const int bh = xcd*4 + unit;        // 4 (b,h)-slices per XCD for L2 locality
  const int b = bh >> 3, h = bh & 7;
  const int q0 = cidx*64;

  const int tid = threadIdx.x;
  const int lane = tid & 63;
  const int wid  = tid >> 6;          // wave owns rows wid*16..+15
  const int ln15 = lane & 15, ln4 = lane >> 4;

  // ---------- phase 1: P[64q][48c] = Q @ [W_off;W_attn]^T (head h) ----------
  f32x4 pacc[3];
  #pragma unroll
  for (int i=0;i<3;++i) pacc[i] = (f32x4){0.f,0.f,0.f,0.f};

  f32x4 wv[3];
  auto loadW = [&](int k0){
    #pragma unroll
    for (int i=0;i<3;++i){
      const int ct = tid + 256*i;            // 0..767
      const int row = ct >> 4, c = ct & 15;  // row 0..47
      f32x4 vv = (f32x4){0.f,0.f,0.f,0.f};
      if (row < 24)      vv = *(const f32x4*)(W_off  + (size_t)(h*24+row)*C_ + k0 + c*4);
      else if (row < 36) vv = *(const f32x4*)(W_attn + (size_t)(h*12+row-24)*C_ + k0 + c*4);
      wv[i] = vv;
    }
  };
  auto writeW = [&](){
    #pragma unroll
    for (int i=0;i<3;++i){
      const int ct = tid + 256*i;
      const int row = ct >> 4, c = ct & 15;
      const u32 p0 = cvtpk(wv[i].x, wv[i].y), p1 = cvtpk(wv[i].z, wv[i].w);
      const int cc = c >> 1;
      uint2v pk; pk.x = p0; pk.y = p1;
      *(uint2v*)&Ws[row*32 + ((cc ^ (row&7))<<2) + (c&1)*2] = pk;
    }
  };

  loadW(0);
  #pragma unroll
  for (int kt=0; kt<4; ++kt){
    const int k0 = kt*BK;
    // Q tile DMA (validated MODE0/1 stage pattern; rows clamped within batch b)
    #pragma unroll
    for (int i=0;i<4;++i){
      const int rl = wid*16 + i*4 + (lane>>4);      // 0..63
      const int rg = b*S_ + min(q0 + rl, S_-1);
      const int c = lane & 15, cs = c ^ (rl & 15);
      __builtin_amdgcn_global_load_lds(query + (size_t)rg*C_ + k0 + cs*4,
          &QsF[(wid*16 + i*4)*64], 16, 0, 0);
    }
    writeW();                       // waits wv(kt)
    if (kt < 3) loadW(k0 + BK);     // in flight across sync+compute+sync
    __syncthreads();
    #pragma unroll
    for (int ks=0; ks<2; ++ks){
      const int qrow = wid*16 + ln15;
      const int ch = ks*8 + ln4*2;
      const int c1 = ch ^ (qrow&15), c2 = (ch+1) ^ (qrow&15);
      const f32x4 lo = *(const f32x4*)&QsF[qrow*64 + c1*4];
      const f32x4 hi = *(const f32x4*)&QsF[qrow*64 + c2*4];
      uint4v uu;
      uu.x = cvtpk(lo.x, lo.y); uu.y = cvtpk(lo.z, lo.w);
      uu.z = cvtpk(hi.x, hi.y); uu.w = cvtpk(hi.z, hi.w);
      const short8v af = __builtin_bit_cast(short8v, uu);
      #pragma unroll
      for (int ni=0;ni<3;++ni){
        const int wrow = ni*16 + ln15;
        const int c = ks*4 + ln4;
        const short8v bfr = *(const short8v*)&Ws[wrow*32 + ((c ^ (wrow&7))<<2)];
        pacc[ni] = __builtin_amdgcn_mfma_f32_16x16x32_bf16(af, bfr, pacc[ni], 0, 0, 0);
      }
    }
    __syncthreads();
  }

  // P epilogue -> LDS record [64][40] (cols 0..23 offsets, 24..35 softmaxed attn)
  #pragma unroll
  for (int ni=0;ni<3;++ni){
    const int col = ni*16 + ln15;
    if (col < 24) {
      const float bv = b_off[h*24 + col];
      #pragma unroll
      for (int j=0;j<4;++j){
        const int qr = wid*16 + ln4*4 + j;
        rec[qr*40 + col] = f2bf(pacc[ni][j] + bv);
      }
    } else if (col < 36) {
      const float bv = b_attn[h*12 + col - 24];
      #pragma unroll
      for (int j=0;j<4;++j){
        const int qr = wid*16 + ln4*4 + j;
        const float vv = pacc[ni][j] + bv;
        float mx = vv;
        mx = fmaxf(mx, __shfl_xor(mx, 1));
        mx = fmaxf(mx, __shfl_xor(mx, 2));
        const float e = __expf(vv - mx);
        float ssum = e;
        ssum += __shfl_xor(ssum, 1);
        ssum += __shfl_xor(ssum, 2);
        rec[qr*40 + col] = f2bf(e/ssum);
      }
    }
  }
  __syncthreads();

  // ---------- phase 2: gather (round-15 v7 arithmetic, records from LDS) ----------
  const int dh0 = (tid & 3) * 8;
  const int qloc = tid >> 2;
  const int q = q0 + qloc;
  if (q < S_) {
    const size_t r = (size_t)b*S_ + q;
    const float refx = refp[r*2+0], refy = refp[r*2+1];
    const char* vb = (const char*)(v + (size_t)bh * S_ * DH);

    const u16* rp = rec + (size_t)qloc*40;
    us8 so0 = *(const us8*)(rp);
    us8 so1 = *(const us8*)(rp + 8);
    us8 so2 = *(const us8*)(rp + 16);
    us4 sa0 = *(const us4*)(rp + 24);
    us4 sa1 = *(const us4*)(rp + 28);
    us4 sa2 = *(const us4*)(rp + 32);
    u16 soarr[24]; u16 saarr[12];
    #pragma unroll
    for (int i=0;i<8;++i){ soarr[i]=so0[i]; soarr[8+i]=so1[i]; soarr[16+i]=so2[i]; }
    #pragma unroll
    for (int i=0;i<4;++i){ saarr[i]=sa0[i]; saarr[4+i]=sa1[i]; saarr[8+i]=sa2[i]; }

    f32x2 acc0 = (f32x2){0.f,0.f}, acc1 = acc0, acc2 = acc0, acc3 = acc0;
    const int WLs[3]={152,76,38}, HLs[3]={100,50,25}, STs[3]={0,15200,19000};
    const u32 ch2 = (u32)(dh0*2);
    #pragma unroll
    for (int l=0;l<3;++l) {
      const int Wl=WLs[l], Hl=HLs[l];
      const float rxl = refx*(float)Wl - 0.5f;   // ix = ref*W + off - 0.5 (normalizer folded)
      const float ryl = refy*(float)Hl - 0.5f;
      const char* vbl = vb + (size_t)STs[l]*DH*2;
      #pragma unroll
      for (int p=0;p<4;++p) {
        const int idx = l*4 + p;
        const float ix = rxl + bf2f(soarr[2*idx+0]);
        const float iy = ryl + bf2f(soarr[2*idx+1]);
        const float aw = bf2f(saarr[idx]);
        const float x0f = floorf(ix), y0f = floorf(iy);
        const float wx1 = ix-x0f, wy1 = iy-y0f;
        const int x0 = (int)x0f, y0 = (int)y0f;
        const int x1 = x0+1, y1 = y0+1;
        const float wx0z = ((u32)x0 < (u32)Wl) ? (1.f-wx1) : 0.f;
        const float wx1z = ((u32)x1 < (u32)Wl) ? wx1 : 0.f;
        const float wy0z = ((u32)y0 < (u32)Hl) ? aw*(1.f-wy1) : 0.f;
        const float wy1z = ((u32)y1 < (u32)Hl) ? aw*wy1 : 0.f;
        const int xi0 = min(max(x0,0),Wl-1), xi1 = min(max(x1,0),Wl-1);
        const int yi0 = min(max(y0,0),Hl-1), yi1 = min(max(y1,0),Hl-1);
        const u32 rb0 = (u32)(yi0*Wl)*64u + ch2;
        const u32 rb1 = (u32)(yi1*Wl)*64u + ch2;
        const uint4v t00 = *(const uint4v*)(vbl + rb0 + (u32)xi0*64u);
        const uint4v t01 = *(const uint4v*)(vbl + rb0 + (u32)xi1*64u);
        const uint4v t10 = *(const uint4v*)(vbl + rb1 + (u32)xi0*64u);
        const uint4v t11 = *(const uint4v*)(vbl + rb1 + (u32)xi1*64u);
        const float w00 = wx0z*wy0z, w01 = wx1z*wy0z;
        const float w10 = wx0z*wy1z, w11 = wx1z*wy1z;
        f32x2 W00 = (f32x2){w00,w00}, W01 = (f32x2){w01,w01};
        f32x2 W10 = (f32x2){w10,w10}, W11 = (f32x2){w11,w11};
        acc0 = pkfma(unpk(t00.x), W00, acc0);
        acc1 = pkfma(unpk(t00.y), W00, acc1);
        acc2 = pkfma(unpk(t00.z), W00, acc2);
        acc3 = pkfma(unpk(t00.w), W00, acc3);
        acc0 = pkfma(unpk(t01.x), W01, acc0);
        acc1 = pkfma(unpk(t01.y), W01, acc1);
        acc2 = pkfma(unpk(t01.z), W01, acc2);
        acc3 = pkfma(unpk(t01.w), W01, acc3);
        acc0 = pkfma(unpk(t10.x), W10, acc0);
        acc1 = pkfma(unpk(t10.y), W10, acc1);
        acc2 = pkfma(unpk(t10.z), W10, acc2);
        acc3 = pkfma(unpk(t10.w), W10, acc3);
        acc0 = pkfma(unpk(t11.x), W11, acc0);
        acc1 = pkfma(unpk(t11.y), W11, acc1);
        acc2 = pkfma(unpk(t11.z), W11, acc2);
        acc3 = pkfma(unpk(t11.w), W11, acc3);
      }
    }
    uint4v o;
    o.x = cvtpk(acc0.x, acc0.y); o.y = cvtpk(acc1.x, acc1.y);
    o.z = cvtpk(acc2.x, acc2.y); o.w = cvtpk(acc3.x, acc3.y);
    *(uint4v*)(tmp + r*C_ + (size_t)h*DH + dh0) = o;
  }
}

extern "C" void kernel_launch(void* const* d_in, const int* in_sizes, int n_in,
                              void* d_out, int out_size, void* d_ws, size_t ws_size,
                              hipStream_t stream) {
  (void)in_sizes; (void)n_in; (void)out_size; (void)ws_size;
  const float* query = (const float*)d_in[0];
  const float* value = (const float*)d_in[1];
  const float* refp  = (const float*)d_in[4];
  const float* W_off = (const float*)d_in[5];
  const float* b_off = (const float*)d_in[6];
  const float* W_attn= (const float*)d_in[7];
  const float* b_attn= (const float*)d_in[8];
  const float* W_val = (const float*)d_in[9];
  const float* b_val = (const float*)d_in[10];
  const float* W_out = (const float*)d_in[11];
  const float* b_out = (const float*)d_in[12];
  float* out = (float*)d_out;

  char* ws = (char*)d_ws;
  constexpr size_t V_BYTES = (size_t)BS_*C_*2;     // 40.9 MB: v bf16 (b,h,s,dh)
  u16* v   = (u16*)(ws);
  u16* tmp = (u16*)(ws + V_BYTES);

  dim3 blk(256);
  hipLaunchKernelGGL(k_projF, dim3(2*NPAN), blk, 0, stream,
                     (const void*)value, W_val, b_val, (void*)v);
  hipLaunchKernelGGL(k_sampleQ, dim3(8*4*NCH), blk, 0, stream,
                     v, query, W_off, b_off, W_attn, b_attn, refp, tmp);
  hipLaunchKernelGGL(k_gemm2F, dim3(2*NPAN), blk, 0, stream,
                     (const void*)tmp, W_out, b_out, (void*)out);
}

// Round 18
// 241.110 us; speedup vs baseline: 1.1075x; 1.0172x over previous
//
#include <hip/hip_runtime.h>

typedef unsigned short u16;
typedef unsigned int u32;
typedef __attribute__((ext_vector_type(8))) short short8v;   // 8 bf16 MFMA frag
typedef __attribute__((ext_vector_type(4))) float f32x4;
typedef __attribute__((ext_vector_type(2))) float f32x2;
typedef __attribute__((ext_vector_type(4))) unsigned int uint4v;
typedef __attribute__((ext_vector_type(2))) unsigned int uint2v;
typedef __attribute__((ext_vector_type(8))) unsigned short us8;
typedef __attribute__((ext_vector_type(4))) unsigned short us4;

#define B_   4
#define S_   19950
#define C_   256
#define NH   8
#define DH   32
#define BS_  (B_*S_)          // 79800

#define BM 64                 // 64-row M-panels
#define BN 128
#define BK 64
#define NPAN 1248             // padded to /8 (tail rows clamped+guarded)

__device__ __forceinline__ float bf2f(u16 u){ u32 x=((u32)u)<<16; float f; __builtin_memcpy(&f,&x,4); return f; }
__device__ __forceinline__ u16 f2bf(float f){ u32 x; __builtin_memcpy(&x,&f,4); x += 0x7fffu + ((x>>16)&1u); return (u16)(x>>16); }
__device__ __forceinline__ u32 cvtpk(float a, float b){ u32 r; asm("v_cvt_pk_bf16_f32 %0, %1, %2" : "=v"(r) : "v"(a), "v"(b)); return r; }
__device__ __forceinline__ f32x2 pkfma(f32x2 a, f32x2 b, f32x2 d){
  asm("v_pk_fma_f32 %0, %1, %2, %0" : "+v"(d) : "v"(a), "v"(b)); return d;
}
__device__ __forceinline__ f32x2 unpk(u32 p){
  uint2v u; u.x = p<<16; u.y = p & 0xffff0000u; return __builtin_bit_cast(f32x2, u);
}

// ====== MFMA GEMM core (round-13/15 structure + counted-vmcnt barrier-1) ======
// MODE 0: A=value f32 -> v bf16 permuted (b,h,s,dh)
// MODE 1: A=query f32 -> soff/sattn HEAD-MAJOR [(h*4+b)][q][24|12]
// MODE 2: A=tmp bf16  -> out f32.
// Per k-step: A-DMA (oldest vmem) | writeB | loadB(next) | vmcnt(8)+lgkmcnt(0)+s_barrier
// -> B prefetch stays in flight ACROSS compute; drained by barrier-2's full sync.
template<int MODE>
__device__ __forceinline__ void gemm_core(int g, u32* smem,
    const void* __restrict__ Aany, const float* __restrict__ Wmain,
    const float* __restrict__ Wattn, const float* __restrict__ bmain,
    const float* __restrict__ battn, void* __restrict__ out0, u16* __restrict__ out1)
{
  constexpr int NX = (MODE==1) ? 3 : 2;
  float* Asf = (float*)smem;                        // MODE0/1: f32[64][64]
  u16*  Asb  = (u16*)smem;                          // MODE2:   bf16[64][64]
  u32*  Bs   = smem + ((MODE==2) ? 2048 : 4096);    // bf16[128][64]

  const int tid = threadIdx.x;
  const int x = (g>>3) % NX;
  const int y = ((g>>3)/NX)*8 + (g&7);   // XCD-paired: col-blocks of one A-panel 8 apart -> same XCD
  const int m0 = y * BM;
  const int n0 = x * BN;
  const int lane = tid & 63;
  const int wid  = tid >> 6;
  const int wm = wid >> 1, wn = wid & 1;
  const int ln15 = lane & 15, ln4 = lane >> 4;

  f32x4 acc[2][4];
  #pragma unroll
  for (int i=0;i<2;++i){
    #pragma unroll
    for (int j=0;j<4;++j) acc[i][j] = (f32x4){0.f,0.f,0.f,0.f};
  }

  f32x4 bvv[8];
  auto loadB = [&](int k0){
    #pragma unroll
    for (int i=0;i<8;++i){
      const int ct = tid + 256*i;
      const int row = ct >> 4, c = ct & 15;
      const int n = n0 + row;
      f32x4 vv = (f32x4){0.f,0.f,0.f,0.f};
      if constexpr (MODE==1) {
        if (n < 192)      vv = *(const f32x4*)(Wmain + (size_t)n*C_ + k0 + c*4);
        else if (n < 288) vv = *(const f32x4*)(Wattn + (size_t)(n-192)*C_ + k0 + c*4);
      } else {
        vv = *(const f32x4*)(Wmain + (size_t)n*C_ + k0 + c*4);
      }
      bvv[i] = vv;
    }
  };

  loadB(0);   // prologue

  #pragma unroll
  for (int kt=0; kt<4; ++kt) {
    const int k0 = kt*BK;
    // ---- A async DMA to LDS first (oldest vmem ops this step) ----
    if constexpr (MODE==2) {
      const u16* Ab = (const u16*)Aany;
      #pragma unroll
      for (int i=0;i<2;++i){
        const int rl = wid*16 + i*8 + (lane>>3);       // row 0..63
        const int rg = min(m0 + rl, BS_-1);
        const int c = lane & 7, cs = c ^ (rl & 7);
        __builtin_amdgcn_global_load_lds(Ab + (size_t)rg*C_ + k0 + cs*8,
            &Asb[(wid*16 + i*8)*64], 16, 0, 0);
      }
    } else {
      const float* Ab = (const float*)Aany;
      #pragma unroll
      for (int i=0;i<4;++i){
        const int rl = wid*16 + i*4 + (lane>>4);       // row 0..63
        const int rg = min(m0 + rl, BS_-1);
        const int c = lane & 15, cs = c ^ (rl & 15);
        __builtin_amdgcn_global_load_lds(Ab + (size_t)rg*C_ + k0 + cs*4,
            &Asf[(wid*16 + i*4)*64], 16, 0, 0);
      }
    }
    __builtin_amdgcn_sched_barrier(0);   // pin: DMA issued before B loads (oldest = DMA)
    // ---- B cvt + swizzled LDS write (waits bvv), then issue next B loads ----
    #pragma unroll
    for (int i=0;i<8;++i){
      const int ct = tid + 256*i;
      const int row = ct >> 4, c = ct & 15;
      const u32 p0 = cvtpk(bvv[i].x, bvv[i].y), p1 = cvtpk(bvv[i].z, bvv[i].w);
      const int cc = c >> 1;
      uint2v pk; pk.x = p0; pk.y = p1;
      *(uint2v*)&Bs[row*32 + ((cc ^ (row&7))<<2) + (c&1)*2] = pk;
    }
    if (kt < 3) {
      loadB(k0 + BK);   // newest vmem: stays in flight across barrier + compute
      asm volatile("s_waitcnt vmcnt(8) lgkmcnt(0)" ::: "memory");  // drain DMA+keep B loads
    } else {
      asm volatile("s_waitcnt vmcnt(0) lgkmcnt(0)" ::: "memory");
    }
    __builtin_amdgcn_s_barrier();
    __builtin_amdgcn_sched_barrier(0);
    // ---- compute: 2 k-sub of 32, 2x4 frags ----
    #pragma unroll
    for (int ks=0; ks<2; ++ks) {
      short8v af[2], bfr[4];
      #pragma unroll
      for (int mi=0;mi<2;++mi){
        const int row = wm*32 + mi*16 + ln15;
        if constexpr (MODE==2) {
          const int c = ks*4 + ln4;
          af[mi] = *(const short8v*)&Asb[row*64 + ((c ^ (row&7))<<3)];
        } else {
          const int ch = ks*8 + ln4*2;
          const int c1 = ch ^ (row&15), c2 = (ch+1) ^ (row&15);
          const f32x4 lo = *(const f32x4*)&Asf[row*64 + c1*4];
          const f32x4 hi = *(const f32x4*)&Asf[row*64 + c2*4];
          uint4v uu;
          uu.x = cvtpk(lo.x, lo.y); uu.y = cvtpk(lo.z, lo.w);
          uu.z = cvtpk(hi.x, hi.y); uu.w = cvtpk(hi.z, hi.w);
          af[mi] = __builtin_bit_cast(short8v, uu);
        }
      }
      #pragma unroll
      for (int ni=0;ni<4;++ni){
        const int row = wn*64 + ni*16 + ln15;
        const int c = ks*4 + ln4;
        bfr[ni] = *(const short8v*)&Bs[row*32 + ((c ^ (row&7))<<2)];
      }
      #pragma unroll
      for (int mi=0;mi<2;++mi){
        #pragma unroll
        for (int ni=0;ni<4;++ni)
          acc[mi][ni] = __builtin_amdgcn_mfma_f32_16x16x32_bf16(af[mi], bfr[ni], acc[mi][ni], 0, 0, 0);
      }
    }
    __syncthreads();   // barrier-2: full drain (B prefetch has had the compute phase to land)
  }

  // ==== epilogue via LDS repack (round-13 validated): 16B coalesced stores ====
  if constexpr (MODE==2) {
    float* Cs = (float*)smem;
    float* outp = (float*)out0;
    #pragma unroll
    for (int p=0;p<2;++p){
      if (wm == p) {
        #pragma unroll
        for (int mi=0;mi<2;++mi){
          #pragma unroll
          for (int ni=0;ni<4;++ni){
            const int col = wn*64 + ni*16 + ln15;
            const float bv = bmain[n0 + col];
            #pragma unroll
            for (int j=0;j<4;++j){
              const int rl = mi*16 + ln4*4 + j;
              Cs[rl*132 + col] = acc[mi][ni][j] + bv;
            }
          }
        }
      }
      __syncthreads();
      #pragma unroll
      for (int i=0;i<4;++i){
        const int c = i*256 + tid;
        const int row = c >> 5, ch = c & 31;
        const int m = m0 + p*32 + row;
        if (m < BS_) {
          const f32x4 vv = *(const f32x4*)&Cs[row*132 + ch*4];
          *(f32x4*)(outp + (size_t)m*C_ + n0 + ch*4) = vv;
        }
      }
      __syncthreads();
    }
  } else {
    u16* Cs = (u16*)smem;
    #pragma unroll
    for (int mi=0;mi<2;++mi){
      #pragma unroll
      for (int ni=0;ni<4;++ni){
        const int col = wn*64 + ni*16 + ln15;
        const int n = n0 + col;
        if (MODE==1 && n >= 288) continue;
        float bias;
        if constexpr (MODE==1) bias = (n < 192) ? bmain[n] : battn[n-192];
        else                   bias = bmain[n];
        if (MODE==1 && n >= 192) {
          #pragma unroll
          for (int j=0;j<4;++j){
            const int row = wm*32 + mi*16 + ln4*4 + j;
            const float vv = acc[mi][ni][j] + bias;
            float mx = vv;
            mx = fmaxf(mx, __shfl_xor(mx, 1));
            mx = fmaxf(mx, __shfl_xor(mx, 2));
            const float e = __expf(vv - mx);
            float ssum = e;
            ssum += __shfl_xor(ssum, 1);
            ssum += __shfl_xor(ssum, 2);
            Cs[row*136 + col] = f2bf(e/ssum);
          }
        } else {
          #pragma unroll
          for (int j=0;j<4;++j){
            const int row = wm*32 + mi*16 + ln4*4 + j;
            Cs[row*136 + col] = f2bf(acc[mi][ni][j] + bias);
          }
        }
      }
    }
    __syncthreads();
    #pragma unroll
    for (int i=0;i<4;++i){
      const int c = i*256 + tid;
      const int row = c >> 4, ch = c & 15;
      const int m = m0 + row;
      if (m >= BS_) continue;
      const int colg = n0 + ch*8;
      const int bq = m / S_, sq = m - bq*S_;
      if constexpr (MODE==0) {
        const uint4v vv = *(const uint4v*)&Cs[row*136 + ch*8];
        u16* vout = (u16*)out0;
        const int h = colg >> 5, dh0 = colg & 31;
        *(uint4v*)(vout + ((size_t)(bq*NH+h)*S_ + sq)*DH + dh0) = vv;
      } else {
        if (colg < 192) {
          const uint4v vv = *(const uint4v*)&Cs[row*136 + ch*8];
          u16* soff = (u16*)out0;
          const int hh = colg / 24, cc = colg - hh*24;
          *(uint4v*)(soff + (((size_t)hh*4 + bq)*S_ + sq)*24 + cc) = vv;
        } else if (colg < 288) {
          #pragma unroll
          for (int half=0; half<2; ++half){
            const int nl2 = colg + half*4 - 192;
            const int hh = nl2 / 12, cc = nl2 - hh*12;
            const uint2v vv = *(const uint2v*)&Cs[row*136 + ch*8 + half*4];
            *(uint2v*)(out1 + (((size_t)hh*4 + bq)*S_ + sq)*12 + cc) = vv;
          }
        }
      }
    }
  }
}

// ---- FUSED projections: blocks [0,2496) = vproj (MODE0), [2496,6240) = qproj (MODE1) ----
__global__ __launch_bounds__(256) void k_projF(
    const void* __restrict__ value, const float* __restrict__ Wv,
    const float* __restrict__ bv, void* __restrict__ vout,
    const void* __restrict__ query, const float* __restrict__ Wo,
    const float* __restrict__ Wa, const float* __restrict__ bo,
    const float* __restrict__ ba, void* __restrict__ soff, u16* __restrict__ sattn)
{
  __shared__ u32 smem[8192];   // 32 KB
  const int g = blockIdx.x;
  if (g < 2*NPAN) gemm_core<0>(g,          smem, value, Wv, nullptr, bv, nullptr, vout, nullptr);
  else            gemm_core<1>(g - 2*NPAN, smem, query, Wo, Wa,      bo, ba,      soff, sattn);
}

__global__ __launch_bounds__(256) void k_gemm2F(const void* __restrict__ A,
    const float* __restrict__ W, const float* __restrict__ b, void* __restrict__ o)
{
  __shared__ u32 smem[6144];   // 24 KB
  gemm_core<2>(blockIdx.x, smem, A, W, nullptr, b, nullptr, o, nullptr);
}

// ==== Sampler v7 (round-15 proven): head-major dense records + v4 arithmetic, cached loads ====
#define NCH 312   // ceil(19950/64) chunks of 64 queries

__global__ __launch_bounds__(256) void k_sample7(const u16* __restrict__ v,
    const u16* __restrict__ soff, const u16* __restrict__ sattn,
    const float* __restrict__ refp, u16* __restrict__ tmp)
{
  const int g = blockIdx.x;
  const int xcd = g & 7, inner = g >> 3;      // inner in [0, 4*NCH)
  const int unit = inner / NCH;               // 0..3
  const int cidx = inner - unit*NCH;
  const int bh = xcd*4 + unit;                // 4 (b,h)-slices per XCD for L2 locality
  const int b = bh >> 3, h = bh & 7;
  const int dh0 = (threadIdx.x & 3) * 8;
  const int q = cidx*64 + (threadIdx.x >> 2);
  if (q >= S_) return;
  const size_t r = (size_t)b*S_ + q;
  const float refx = refp[r*2+0], refy = refp[r*2+1];
  const char* vb = (const char*)(v + (size_t)bh * S_ * DH);

  // head-major dense records: 48B offsets + 24B weights per (h,b,q)
  const u16* sop = soff + (((size_t)h*4 + b)*S_ + q)*24;
  const u16* sap = sattn + (((size_t)h*4 + b)*S_ + q)*12;
  us8 so0 = *(const us8*)(sop);
  us8 so1 = *(const us8*)(sop + 8);
  us8 so2 = *(const us8*)(sop + 16);
  us4 sa0 = *(const us4*)(sap);
  us4 sa1 = *(const us4*)(sap + 4);
  us4 sa2 = *(const us4*)(sap + 8);
  u16 soarr[24]; u16 saarr[12];
  #pragma unroll
  for (int i=0;i<8;++i){ soarr[i]=so0[i]; soarr[8+i]=so1[i]; soarr[16+i]=so2[i]; }
  #pragma unroll
  for (int i=0;i<4;++i){ saarr[i]=sa0[i]; saarr[4+i]=sa1[i]; saarr[8+i]=sa2[i]; }

  f32x2 acc0 = (f32x2){0.f,0.f}, acc1 = acc0, acc2 = acc0, acc3 = acc0;
  const int WLs[3]={152,76,38}, HLs[3]={100,50,25}, STs[3]={0,15200,19000};
  const u32 ch2 = (u32)(dh0*2);
  #pragma unroll
  for (int l=0;l<3;++l) {
    const int Wl=WLs[l], Hl=HLs[l];
    const float rxl = refx*(float)Wl - 0.5f;   // ix = ref*W + off - 0.5 (normalizer folded)
    const float ryl = refy*(float)Hl - 0.5f;
    const char* vbl = vb + (size_t)STs[l]*DH*2;
    #pragma unroll
    for (int p=0;p<4;++p) {
      const int idx = l*4 + p;
      const float ix = rxl + bf2f(soarr[2*idx+0]);
      const float iy = ryl + bf2f(soarr[2*idx+1]);
      const float aw = bf2f(saarr[idx]);
      const float x0f = floorf(ix), y0f = floorf(iy);
      const float wx1 = ix-x0f, wy1 = iy-y0f;
      const int x0 = (int)x0f, y0 = (int)y0f;
      const int x1 = x0+1, y1 = y0+1;
      // separable zeroed weights (validity folded; aw folded into y factors)
      const float wx0z = ((u32)x0 < (u32)Wl) ? (1.f-wx1) : 0.f;
      const float wx1z = ((u32)x1 < (u32)Wl) ? wx1 : 0.f;
      const float wy0z = ((u32)y0 < (u32)Hl) ? aw*(1.f-wy1) : 0.f;
      const float wy1z = ((u32)y1 < (u32)Hl) ? aw*wy1 : 0.f;
      const int xi0 = min(max(x0,0),Wl-1), xi1 = min(max(x1,0),Wl-1);
      const int yi0 = min(max(y0,0),Hl-1), yi1 = min(max(y1,0),Hl-1);
      const u32 rb0 = (u32)(yi0*Wl)*64u + ch2;
      const u32 rb1 = (u32)(yi1*Wl)*64u + ch2;
      const uint4v t00 = *(const uint4v*)(vbl + rb0 + (u32)xi0*64u);
      const uint4v t01 = *(const uint4v*)(vbl + rb0 + (u32)xi1*64u);
      const uint4v t10 = *(const uint4v*)(vbl + rb1 + (u32)xi0*64u);
      const uint4v t11 = *(const uint4v*)(vbl + rb1 + (u32)xi1*64u);
      const float w00 = wx0z*wy0z, w01 = wx1z*wy0z;
      const float w10 = wx0z*wy1z, w11 = wx1z*wy1z;
      f32x2 W00 = (f32x2){w00,w00}, W01 = (f32x2){w01,w01};
      f32x2 W10 = (f32x2){w10,w10}, W11 = (f32x2){w11,w11};
      acc0 = pkfma(unpk(t00.x), W00, acc0);
      acc1 = pkfma(unpk(t00.y), W00, acc1);
      acc2 = pkfma(unpk(t00.z), W00, acc2);
      acc3 = pkfma(unpk(t00.w), W00, acc3);
      acc0 = pkfma(unpk(t01.x), W01, acc0);
      acc1 = pkfma(unpk(t01.y), W01, acc1);
      acc2 = pkfma(unpk(t01.z), W01, acc2);
      acc3 = pkfma(unpk(t01.w), W01, acc3);
      acc0 = pkfma(unpk(t10.x), W10, acc0);
      acc1 = pkfma(unpk(t10.y), W10, acc1);
      acc2 = pkfma(unpk(t10.z), W10, acc2);
      acc3 = pkfma(unpk(t10.w), W10, acc3);
      acc0 = pkfma(unpk(t11.x), W11, acc0);
      acc1 = pkfma(unpk(t11.y), W11, acc1);
      acc2 = pkfma(unpk(t11.z), W11, acc2);
      acc3 = pkfma(unpk(t11.w), W11, acc3);
    }
  }
  uint4v o;
  o.x = cvtpk(acc0.x, acc0.y); o.y = cvtpk(acc1.x, acc1.y);
  o.z = cvtpk(acc2.x, acc2.y); o.w = cvtpk(acc3.x, acc3.y);
  *(uint4v*)(tmp + r*C_ + (size_t)h*DH + dh0) = o;
}

extern "C" void kernel_launch(void* const* d_in, const int* in_sizes, int n_in,
                              void* d_out, int out_size, void* d_ws, size_t ws_size,
                              hipStream_t stream) {
  (void)in_sizes; (void)n_in; (void)out_size; (void)ws_size;
  const float* query = (const float*)d_in[0];
  const float* value = (const float*)d_in[1];
  const float* refp  = (const float*)d_in[4];
  const float* W_off = (const float*)d_in[5];
  const float* b_off = (const float*)d_in[6];
  const float* W_attn= (const float*)d_in[7];
  const float* b_attn= (const float*)d_in[8];
  const float* W_val = (const float*)d_in[9];
  const float* b_val = (const float*)d_in[10];
  const float* W_out = (const float*)d_in[11];
  const float* b_out = (const float*)d_in[12];
  float* out = (float*)d_out;

  char* ws = (char*)d_ws;
  constexpr size_t V_BYTES    = (size_t)BS_*C_*2;     // 40.9 MB: v bf16 (b,h,s,dh)
  constexpr size_t SOFF_BYTES = (size_t)BS_*24*NH*2;  // 30.6 MB head-major
  constexpr size_t SATTN_BYTES= (size_t)BS_*12*NH*2;  // 15.3 MB head-major
  u16* v     = (u16*)(ws);
  u16* soff  = (u16*)(ws + V_BYTES);
  u16* sattn = (u16*)(ws + V_BYTES + SOFF_BYTES);
  u16* tmp   = (u16*)(ws + V_BYTES + SOFF_BYTES + SATTN_BYTES);

  dim3 blk(256);
  hipLaunchKernelGGL(k_projF, dim3(5*NPAN), blk, 0, stream,
                     (const void*)value, W_val, b_val, (void*)v,
                     (const void*)query, W_off, W_attn, b_off, b_attn,
                     (void*)soff, sattn);
  hipLaunchKernelGGL(k_sample7, dim3(8*4*NCH), blk, 0, stream, v, soff, sattn, refp, tmp);
  hipLaunchKernelGGL(k_gemm2F, dim3(2*NPAN), blk, 0, stream,
                     (const void*)tmp, W_out, b_out, (void*)out);
}